// Round 1
// baseline (399.298 us; speedup 1.0000x reference)
//
#include <hip/hip_runtime.h>

#define PD(i) ((i) + ((i) >> 5))   // LDS pad: +1 slot per 32 to break power-of-2 strides
#define BLD 524288                 // 8*2048*32

__device__ __forceinline__ float2 cadd(float2 a, float2 b){ return make_float2(a.x+b.x, a.y+b.y); }
__device__ __forceinline__ float2 csub(float2 a, float2 b){ return make_float2(a.x-b.x, a.y-b.y); }
__device__ __forceinline__ float2 cmul(float2 a, float2 b){ return make_float2(a.x*b.x - a.y*b.y, a.x*b.y + a.y*b.x); }
__device__ __forceinline__ float2 cmuli(float2 a, float s){ return make_float2(-s*a.y, s*a.x); }

// DFT-8: A_j = sum_l a_l * exp(SGN*2*pi*i*j*l/8)
template<int SGN>
__device__ __forceinline__ void dft8(float2 a[8]) {
  const float sgn = (float)SGN;
  const float C8 = 0.70710678118654752440f;
  float2 e0=a[0], e1=a[2], e2=a[4], e3=a[6];
  float2 o0=a[1], o1=a[3], o2=a[5], o3=a[7];
  float2 t0=cadd(e0,e2), t1=csub(e0,e2), t2=cadd(e1,e3), t3=csub(e1,e3);
  float2 E0=cadd(t0,t2), E2=csub(t0,t2);
  float2 t3i=cmuli(t3,sgn);
  float2 E1=cadd(t1,t3i), E3=csub(t1,t3i);
  float2 s0=cadd(o0,o2), s1=csub(o0,o2), s2=cadd(o1,o3), s3=csub(o1,o3);
  float2 O0=cadd(s0,s2), O2=csub(s0,s2);
  float2 s3i=cmuli(s3,sgn);
  float2 O1=cadd(s1,s3i), O3=csub(s1,s3i);
  float2 w1o = make_float2(C8*(O1.x - sgn*O1.y), C8*(O1.y + sgn*O1.x));
  float2 w2o = cmuli(O2, sgn);
  float2 w3o = make_float2(-C8*(O3.x + sgn*O3.y), C8*(sgn*O3.x - O3.y));
  a[0]=cadd(E0,O0); a[4]=csub(E0,O0);
  a[1]=cadd(E1,w1o); a[5]=csub(E1,w1o);
  a[2]=cadd(E2,w2o); a[6]=csub(E2,w2o);
  a[3]=cadd(E3,w3o); a[7]=csub(E3,w3o);
}

// 2048-pt Stockham FFT (radix 8,8,8,4), natural-in natural-out.
// Input in bufA (padded addressing PD), result in bufA. Caller syncs before call.
template<int SGN>
__device__ void fft2048(float2* bufA, float2* bufB, const float2* twd, int tid)
{
  const float sgn = (float)SGN;
  { // stage A: ncur=2048, s=1
    float2 a[8];
    #pragma unroll
    for (int j=0;j<8;j++) a[j] = bufA[PD(tid + 256*j)];
    dft8<SGN>(a);
    float2 tw = twd[tid];
    float2 w1 = make_float2(tw.x, sgn*tw.y), wj = w1;
    #pragma unroll
    for (int j=1;j<8;j++){ a[j] = cmul(a[j], wj); wj = cmul(wj, w1); }
    #pragma unroll
    for (int j=0;j<8;j++) bufB[PD(8*tid + j)] = a[j];
  }
  __syncthreads();
  { // stage B: ncur=256, s=8
    float2 a[8];
    #pragma unroll
    for (int j=0;j<8;j++) a[j] = bufB[PD(tid + 256*j)];
    dft8<SGN>(a);
    int p = tid >> 3, q = tid & 7;
    float2 tw = twd[p << 3];
    float2 w1 = make_float2(tw.x, sgn*tw.y), wj = w1;
    #pragma unroll
    for (int j=1;j<8;j++){ a[j] = cmul(a[j], wj); wj = cmul(wj, w1); }
    int base = q + (p << 6);
    #pragma unroll
    for (int j=0;j<8;j++) bufA[PD(base + (j<<3))] = a[j];
  }
  __syncthreads();
  { // stage C: ncur=32, s=64
    float2 a[8];
    #pragma unroll
    for (int j=0;j<8;j++) a[j] = bufA[PD(tid + 256*j)];
    dft8<SGN>(a);
    int p = tid >> 6, q = tid & 63;
    float2 tw = twd[p << 6];
    float2 w1 = make_float2(tw.x, sgn*tw.y), wj = w1;
    #pragma unroll
    for (int j=1;j<8;j++){ a[j] = cmul(a[j], wj); wj = cmul(wj, w1); }
    int base = q + (p << 9);
    #pragma unroll
    for (int j=0;j<8;j++) bufB[PD(base + (j<<6))] = a[j];
  }
  __syncthreads();
  { // stage D: radix-4, ncur=4, s=512, p=0 (no twiddle)
    #pragma unroll
    for (int h=0; h<2; h++){
      int q = tid + (h<<8);
      float2 b0 = bufB[PD(q)], b1 = bufB[PD(q+512)], b2 = bufB[PD(q+1024)], b3 = bufB[PD(q+1536)];
      float2 t0=cadd(b0,b2), t1=csub(b0,b2), t2=cadd(b1,b3), t3=csub(b1,b3);
      float2 t3i=cmuli(t3,sgn);
      bufA[PD(q)]      = cadd(t0,t2);
      bufA[PD(q+512)]  = cadd(t1,t3i);
      bufA[PD(q+1024)] = csub(t0,t2);
      bufA[PD(q+1536)] = csub(t1,t3i);
    }
  }
  __syncthreads();
}

// One block per (b,d) problem. 256 threads; thread owns bins {4t..4t+3} + mirrors.
template<bool TRANSP>
__global__ __launch_bounds__(256, 1) void vmd_main(const float* __restrict__ xg,
                                                   float* __restrict__ uout,
                                                   float* __restrict__ omout)
{
  __shared__ float2 sbufA[2112];
  __shared__ float2 sbufB[2112];
  __shared__ float2 stwd[1024];
  __shared__ float  sred[24];
  __shared__ float  somsh[3];

  const int tid = threadIdx.x;
  const int blk = blockIdx.x;
  const int b = blk >> 5;
  const int d = blk & 31;
  const float inv2048 = 1.0f/2048.0f;

  for (int j = tid; j < 1024; j += 256) {
    double th = 3.14159265358979323846 * (double)j / 1024.0;  // 2*pi*j/2048
    stwd[j] = make_float2((float)cos(th), (float)sin(th));
  }

  int idxs[8];
  #pragma unroll
  for (int c = 0; c < 4; c++) {
    int iL = 4*tid + c;
    idxs[c]   = iL;
    idxs[c+4] = (iL == 0) ? 1024 : (2048 - iL);
  }

  float xv[8];
  #pragma unroll
  for (int e = 0; e < 8; e++) xv[e] = xg[(b*2048 + idxs[e])*32 + d];

  // X_shift = FFT(x * (-1)^t)   (fftshift folded into input parity)
  #pragma unroll
  for (int e = 0; e < 8; e++) {
    float v = (idxs[e] & 1) ? -xv[e] : xv[e];
    sbufA[PD(idxs[e])] = make_float2(v, 0.0f);
  }
  __syncthreads();
  fft2048<-1>(sbufA, sbufB, stwd, tid);
  float2 X[8];
  #pragma unroll
  for (int e = 0; e < 8; e++) X[e] = sbufA[PD(idxs[e])];
  __syncthreads();

  float2 U[3][8];
  float2 S[8];
  float lam[8];
  #pragma unroll
  for (int e = 0; e < 8; e++) {
    S[e] = make_float2(0.f, 0.f); lam[e] = 0.f;
    #pragma unroll
    for (int k = 0; k < 3; k++) U[k][e] = make_float2(0.f, 0.f);
  }
  float om[3] = {0.f, 0.f, 0.f};

  for (int iter = 0; iter < 100; iter++) {
    float sf[3], sp[3];
    #pragma unroll
    for (int k = 0; k < 3; k++) {
      sf[k] = 0.f; sp[k] = 0.f;
      #pragma unroll
      for (int c = 0; c < 4; c++) {
        float fl = (float)(idxs[c]   - 1024) * inv2048;
        float fh = (float)(idxs[c+4] - 1024) * inv2048;
        float2 numl = make_float2(X[c].x   - (S[c].x   - U[k][c].x)   + 0.5f*lam[c],
                                  X[c].y   - (S[c].y   - U[k][c].y));
        float2 numh = make_float2(X[c+4].x - (S[c+4].x - U[k][c+4].x) + 0.5f*lam[c+4],
                                  X[c+4].y - (S[c+4].y - U[k][c+4].y));
        float dl = fl - om[k], dh = fh - om[k];
        float rl = __builtin_amdgcn_rcpf(fmaf(4000.0f*dl, dl, 1.0f));
        float rh = __builtin_amdgcn_rcpf(fmaf(4000.0f*dh, dh, 1.0f));
        float2 Vl = make_float2(numl.x*rl, numl.y*rl);
        float2 Vh = make_float2(numh.x*rh, numh.y*rh);
        float2 Ul, Uh;
        if (tid == 0 && c == 0) {           // self-paired bins 0 and 1024
          Ul = make_float2(Vl.x, 0.f);
          Uh = make_float2(Vh.x, 0.f);
        } else {                            // Herm: U_l = 0.5*(V_l + conj(V_h)); U_h = conj(U_l)
          Ul = make_float2(0.5f*(Vl.x + Vh.x), 0.5f*(Vl.y - Vh.y));
          Uh = make_float2(Ul.x, -Ul.y);
        }
        S[c].x   += Ul.x - U[k][c].x;   S[c].y   += Ul.y - U[k][c].y;
        S[c+4].x += Uh.x - U[k][c+4].x; S[c+4].y += Uh.y - U[k][c+4].y;
        U[k][c] = Ul; U[k][c+4] = Uh;
        float pw = Uh.x*Uh.x + Uh.y*Uh.y;   // pos-masked: only f>=0 (hi slots)
        sf[k] = fmaf(fh, pw, sf[k]);
        sp[k] += pw;
      }
    }
    // omega reduction: 6 scalars over 256 threads
    #pragma unroll
    for (int k = 0; k < 3; k++) {
      #pragma unroll
      for (int off = 32; off >= 1; off >>= 1) {
        sf[k] += __shfl_xor(sf[k], off);
        sp[k] += __shfl_xor(sp[k], off);
      }
    }
    {
      const int wv = tid >> 6, ln = tid & 63;
      if (ln == 0) {
        #pragma unroll
        for (int k = 0; k < 3; k++) { sred[wv*6 + k] = sf[k]; sred[wv*6 + 3 + k] = sp[k]; }
      }
    }
    __syncthreads();
    if (tid < 3) {
      float a = sred[tid] + sred[6+tid] + sred[12+tid] + sred[18+tid];
      float p = sred[3+tid] + sred[9+tid] + sred[15+tid] + sred[21+tid];
      somsh[tid] = a / (p + 1e-7f);
    }
    __syncthreads();
    om[0] = somsh[0]; om[1] = somsh[1]; om[2] = somsh[2];

    // lam update: s_time = (-1)^t * (1/L) * FFT_{+}(S_shift)
    #pragma unroll
    for (int e = 0; e < 8; e++) sbufA[PD(idxs[e])] = S[e];
    __syncthreads();
    fft2048<1>(sbufA, sbufB, stwd, tid);
    #pragma unroll
    for (int e = 0; e < 8; e++) {
      float sv = sbufA[PD(idxs[e])].x * inv2048;
      if (idxs[e] & 1) sv = -sv;
      lam[e] += 0.001f * (xv[e] - sv);
    }
    __syncthreads();
  }

  // final: u_k(time) = (-1)^t * (1/L) * FFT_{+}(U_k)
  #pragma unroll
  for (int k = 0; k < 3; k++) {
    #pragma unroll
    for (int e = 0; e < 8; e++) sbufA[PD(idxs[e])] = U[k][e];
    __syncthreads();
    fft2048<1>(sbufA, sbufB, stwd, tid);
    #pragma unroll
    for (int e = 0; e < 8; e++) {
      float uv = sbufA[PD(idxs[e])].x * inv2048;
      if (idxs[e] & 1) uv = -uv;
      if (TRANSP) uout[(((size_t)k*8 + b)*32 + d)*2048 + idxs[e]] = uv;   // ws: [k][b][d][l]
      else        uout[(size_t)k*BLD + ((size_t)b*2048 + idxs[e])*32 + d] = uv;
    }
    __syncthreads();
  }
  if (tid < 3) omout[(b*3 + tid)*32 + d] = somsh[tid];
}

__global__ void vmd_order(const float* __restrict__ omout, int* __restrict__ ord)
{
  __shared__ float m[24];
  int t = threadIdx.x;
  if (t < 24) {
    float s = 0.f;
    for (int dd = 0; dd < 32; dd++) s += omout[t*32 + dd];
    m[t] = s;
  }
  __syncthreads();
  if (t < 8) {
    float v0 = m[t*3], v1 = m[t*3+1], v2 = m[t*3+2];
    int i0 = 0, i1 = 1, i2 = 2;
    if (v1 < v0){ float tv=v0; v0=v1; v1=tv; int ti=i0; i0=i1; i1=ti; }
    if (v2 < v1){ float tv=v1; v1=v2; v2=tv; int ti=i1; i1=i2; i2=ti; }
    if (v1 < v0){ float tv=v0; v0=v1; v1=tv; int ti=i0; i0=i1; i1=ti; }
    ord[t*3] = i0; ord[t*3+1] = i1; ord[t*3+2] = i2;
  }
}

// ws[ord[k]][b][d][l]  ->  out[k][b][l][d]   (coalesced both sides via LDS tile)
__global__ __launch_bounds__(256) void vmd_permute(const float* __restrict__ wsu,
                                                   const int* __restrict__ ord,
                                                   float* __restrict__ out)
{
  __shared__ float tile[32][33];
  int bid = blockIdx.x;
  int lt = bid & 63;
  int b = (bid >> 6) & 7;
  int kpos = bid >> 9;
  int ks = ord[b*3 + kpos];
  int tr = threadIdx.x >> 5;
  int tc = threadIdx.x & 31;
  for (int it = 0; it < 4; it++) {
    int dd = tr + it*8;
    tile[dd][tc] = wsu[(((size_t)ks*8 + b)*32 + dd)*2048 + lt*32 + tc];
  }
  __syncthreads();
  for (int it = 0; it < 4; it++) {
    int ll = tr + it*8;
    out[(size_t)kpos*BLD + ((size_t)b*2048 + lt*32 + ll)*32 + tc] = tile[tc][ll];
  }
}

// fallback: in-place k-plane permutation of d_out
__global__ void vmd_inplace(float* __restrict__ out, const int* __restrict__ ord)
{
  int r = blockIdx.x * 256 + threadIdx.x;   // < 524288
  int b = r >> 16;
  int o0 = ord[b*3], o1 = ord[b*3+1], o2 = ord[b*3+2];
  float v0 = out[(size_t)o0*BLD + r];
  float v1 = out[(size_t)o1*BLD + r];
  float v2 = out[(size_t)o2*BLD + r];
  out[r] = v0;
  out[(size_t)BLD + r] = v1;
  out[(size_t)2*BLD + r] = v2;
}

extern "C" void kernel_launch(void* const* d_in, const int* in_sizes, int n_in,
                              void* d_out, int out_size, void* d_ws, size_t ws_size,
                              hipStream_t stream)
{
  const float* x = (const float*)d_in[0];
  float* out = (float*)d_out;
  const size_t NU = (size_t)3 * BLD;
  size_t need = NU*4 + 768*4 + 24*4;
  if (ws_size >= need) {
    float* wsu  = (float*)d_ws;
    float* wsom = wsu + NU;
    int*   wsord = (int*)(wsom + 768);
    vmd_main<true><<<256, 256, 0, stream>>>(x, wsu, wsom);
    vmd_order<<<1, 64, 0, stream>>>(wsom, wsord);
    vmd_permute<<<1536, 256, 0, stream>>>(wsu, wsord, out);
  } else {
    float* wsom = (float*)d_ws;
    int*   wsord = (int*)(wsom + 768);
    vmd_main<false><<<256, 256, 0, stream>>>(x, out, wsom);
    vmd_order<<<1, 64, 0, stream>>>(wsom, wsord);
    vmd_inplace<<<2048, 256, 0, stream>>>(out, wsord);
  }
}

// Round 2
// 339.770 us; speedup vs baseline: 1.1752x; 1.1752x over previous
//
#include <hip/hip_runtime.h>

#define PD(i) ((i) + ((i) >> 5))   // LDS pad: +1 slot per 32 to break power-of-2 strides
#define BLD 524288                 // 8*2048*32

__device__ __forceinline__ float2 cadd(float2 a, float2 b){ return make_float2(a.x+b.x, a.y+b.y); }
__device__ __forceinline__ float2 csub(float2 a, float2 b){ return make_float2(a.x-b.x, a.y-b.y); }
__device__ __forceinline__ float2 cmul(float2 a, float2 b){ return make_float2(a.x*b.x - a.y*b.y, a.x*b.y + a.y*b.x); }
__device__ __forceinline__ float2 cmuli(float2 a, float s){ return make_float2(-s*a.y, s*a.x); }

// DFT-8: A_j = sum_l a_l * exp(SGN*2*pi*i*j*l/8)  (init FFT only)
template<int SGN>
__device__ __forceinline__ void dft8(float2 a[8]) {
  const float sgn = (float)SGN;
  const float C8 = 0.70710678118654752440f;
  float2 e0=a[0], e1=a[2], e2=a[4], e3=a[6];
  float2 o0=a[1], o1=a[3], o2=a[5], o3=a[7];
  float2 t0=cadd(e0,e2), t1=csub(e0,e2), t2=cadd(e1,e3), t3=csub(e1,e3);
  float2 E0=cadd(t0,t2), E2=csub(t0,t2);
  float2 t3i=cmuli(t3,sgn);
  float2 E1=cadd(t1,t3i), E3=csub(t1,t3i);
  float2 s0=cadd(o0,o2), s1=csub(o0,o2), s2=cadd(o1,o3), s3=csub(o1,o3);
  float2 O0=cadd(s0,s2), O2=csub(s0,s2);
  float2 s3i=cmuli(s3,sgn);
  float2 O1=cadd(s1,s3i), O3=csub(s1,s3i);
  float2 w1o = make_float2(C8*(O1.x - sgn*O1.y), C8*(O1.y + sgn*O1.x));
  float2 w2o = cmuli(O2, sgn);
  float2 w3o = make_float2(-C8*(O3.x + sgn*O3.y), C8*(sgn*O3.x - O3.y));
  a[0]=cadd(E0,O0); a[4]=csub(E0,O0);
  a[1]=cadd(E1,w1o); a[5]=csub(E1,w1o);
  a[2]=cadd(E2,w2o); a[6]=csub(E2,w2o);
  a[3]=cadd(E3,w3o); a[7]=csub(E3,w3o);
}

// 2048-pt Stockham FFT (radix 8,8,8,4), natural-in natural-out. Result in bufA.
template<int SGN>
__device__ void fft2048(float2* bufA, float2* bufB, const float2* twd, int tid)
{
  const float sgn = (float)SGN;
  { // stage A: s=1
    float2 a[8];
    #pragma unroll
    for (int j=0;j<8;j++) a[j] = bufA[PD(tid + 256*j)];
    dft8<SGN>(a);
    float2 tw = twd[tid];
    float2 w1 = make_float2(tw.x, sgn*tw.y), wj = w1;
    #pragma unroll
    for (int j=1;j<8;j++){ a[j] = cmul(a[j], wj); wj = cmul(wj, w1); }
    #pragma unroll
    for (int j=0;j<8;j++) bufB[PD(8*tid + j)] = a[j];
  }
  __syncthreads();
  { // stage B: s=8
    float2 a[8];
    #pragma unroll
    for (int j=0;j<8;j++) a[j] = bufB[PD(tid + 256*j)];
    dft8<SGN>(a);
    int p = tid >> 3, q = tid & 7;
    float2 tw = twd[p << 3];
    float2 w1 = make_float2(tw.x, sgn*tw.y), wj = w1;
    #pragma unroll
    for (int j=1;j<8;j++){ a[j] = cmul(a[j], wj); wj = cmul(wj, w1); }
    int base = q + (p << 6);
    #pragma unroll
    for (int j=0;j<8;j++) bufA[PD(base + (j<<3))] = a[j];
  }
  __syncthreads();
  { // stage C: s=64
    float2 a[8];
    #pragma unroll
    for (int j=0;j<8;j++) a[j] = bufA[PD(tid + 256*j)];
    dft8<SGN>(a);
    int p = tid >> 6, q = tid & 63;
    float2 tw = twd[p << 6];
    float2 w1 = make_float2(tw.x, sgn*tw.y), wj = w1;
    #pragma unroll
    for (int j=1;j<8;j++){ a[j] = cmul(a[j], wj); wj = cmul(wj, w1); }
    int base = q + (p << 9);
    #pragma unroll
    for (int j=0;j<8;j++) bufB[PD(base + (j<<6))] = a[j];
  }
  __syncthreads();
  { // stage D: radix-4, s=512, p=0
    #pragma unroll
    for (int h=0; h<2; h++){
      int q = tid + (h<<8);
      float2 b0 = bufB[PD(q)], b1 = bufB[PD(q+512)], b2 = bufB[PD(q+1024)], b3 = bufB[PD(q+1536)];
      float2 t0=cadd(b0,b2), t1=csub(b0,b2), t2=cadd(b1,b3), t3=csub(b1,b3);
      float2 t3i=cmuli(t3,sgn);
      bufA[PD(q)]      = cadd(t0,t2);
      bufA[PD(q+512)]  = cadd(t1,t3i);
      bufA[PD(q+1024)] = csub(t0,t2);
      bufA[PD(q+1536)] = csub(t1,t3i);
    }
  }
  __syncthreads();
}

// radix-4 DFT, SGN=+1: A_j = sum_l a_l e^{+2pi i jl/4}
__device__ __forceinline__ void dft4p(float2 a[4]){
  float2 t0=cadd(a[0],a[2]), t1=csub(a[0],a[2]), t2=cadd(a[1],a[3]), t3=csub(a[1],a[3]);
  float2 t3i = make_float2(-t3.y, t3.x);  // +i*t3
  a[0]=cadd(t0,t2); a[2]=csub(t0,t2);
  a[1]=cadd(t1,t3i); a[3]=csub(t1,t3i);
}

// one Stockham radix-4 stage of a 1024-pt DFT+ (256 threads, 4 elems/thread)
template<int S, int LS>
__device__ __forceinline__ void f1024_stage(const float2* __restrict__ in,
                                            float2* __restrict__ out,
                                            const float2* __restrict__ twd, int tid){
  float2 a[4];
  #pragma unroll
  for (int j=0;j<4;j++) a[j] = in[PD(tid + 256*j)];
  dft4p(a);
  if (S < 256) {
    int p = tid >> LS;
    int q = tid & (S-1);
    float2 w1 = twd[(2*S)*p];          // W1024^(S*p); 2*S*p < 512 always
    float2 w2 = cmul(w1,w1);
    float2 w3 = cmul(w2,w1);
    a[1]=cmul(a[1],w1); a[2]=cmul(a[2],w2); a[3]=cmul(a[3],w3);
    int base = q + 4*S*p;
    #pragma unroll
    for (int j=0;j<4;j++) out[PD(base + j*S)] = a[j];
  } else {
    #pragma unroll
    for (int j=0;j<4;j++) out[PD(tid + 256*j)] = a[j];
  }
}

// B holds a Hermitian stored-shifted spectrum (2048 entries, PD-addressed).
// Computes z[0..1023] into A, where g[n] = sum_m B[m] e^{+2pi i m n/2048} (real),
// and z[r] = g[2r] + i*g[2r+1]. Caller must __syncthreads() after writing B.
__device__ void herm_fft_half(float2* __restrict__ A, float2* __restrict__ B,
                              const float2* __restrict__ twd, int tid){
  { // stage 1 (s=1) fused with Hermitian even/odd pack
    float2 a[4];
    #pragma unroll
    for (int j=0;j<4;j++){
      int q = tid + 256*j;
      float2 lo = B[PD(q)], hi = B[PD(q+1024)];
      float2 Av = cadd(lo,hi), Bv = csub(lo,hi);
      float2 wq = twd[q];              // W2048^q
      float2 WB = cmul(wq, Bv);
      a[j] = make_float2(Av.x - WB.y, Av.y + WB.x);   // A + i*W*B
    }
    dft4p(a);
    float2 w1 = twd[2*tid];            // W1024^tid
    float2 w2 = cmul(w1,w1);
    float2 w3 = cmul(w2,w1);
    a[1]=cmul(a[1],w1); a[2]=cmul(a[2],w2); a[3]=cmul(a[3],w3);
    #pragma unroll
    for (int j=0;j<4;j++) A[PD(4*tid + j)] = a[j];
  }
  __syncthreads();
  f1024_stage<4,2>(A, B, twd, tid);   __syncthreads();
  f1024_stage<16,4>(B, A, twd, tid);  __syncthreads();
  f1024_stage<64,6>(A, B, twd, tid);  __syncthreads();
  f1024_stage<256,8>(B, A, twd, tid); __syncthreads();
  // result z in A[0..1023]
}

// One block per (b,d) problem. Thread owns stored bins {4t..4t+3} + mirrors.
template<bool TRANSP>
__global__ __launch_bounds__(256, 1) void vmd_main(const float* __restrict__ xg,
                                                   float* __restrict__ uout,
                                                   float* __restrict__ omout)
{
  __shared__ float2 sbufA[2112];
  __shared__ float2 sbufB[2112];
  __shared__ float2 stwd[1024];
  __shared__ float  sred[24];

  const int tid = threadIdx.x;
  const int blk = blockIdx.x;
  const int b = blk >> 5;
  const int d = blk & 31;
  const float inv2048 = 1.0f/2048.0f;

  for (int j = tid; j < 1024; j += 256) {
    double th = 3.14159265358979323846 * (double)j / 1024.0;  // 2*pi*j/2048
    stwd[j] = make_float2((float)cos(th), (float)sin(th));
  }

  int idxs[8];
  float fl[4], fh[4];
  #pragma unroll
  for (int c = 0; c < 4; c++) {
    int iL = 4*tid + c;
    idxs[c]   = iL;
    idxs[c+4] = (iL == 0) ? 1024 : (2048 - iL);
    fl[c] = (float)(idxs[c]   - 1024) * inv2048;
    fh[c] = (float)(idxs[c+4] - 1024) * inv2048;
  }

  float xv[8];
  #pragma unroll
  for (int e = 0; e < 8; e++) xv[e] = xg[(b*2048 + idxs[e])*32 + d];

  // X_shift = FFT(x * (-1)^t)  (fftshift folded into input parity)
  #pragma unroll
  for (int e = 0; e < 8; e++) {
    float v = (idxs[e] & 1) ? -xv[e] : xv[e];
    sbufA[PD(idxs[e])] = make_float2(v, 0.0f);
  }
  __syncthreads();
  fft2048<-1>(sbufA, sbufB, stwd, tid);
  float2 X[8];
  #pragma unroll
  for (int e = 0; e < 8; e++) X[e] = sbufA[PD(idxs[e])];
  // no sync needed: next write to sbufA is after the combined barrier below

  float2 U[3][8];
  float2 S[8];
  float lam[8];
  #pragma unroll
  for (int e = 0; e < 8; e++) {
    S[e] = make_float2(0.f, 0.f); lam[e] = 0.f;
    #pragma unroll
    for (int k = 0; k < 3; k++) U[k][e] = make_float2(0.f, 0.f);
  }
  float om[3] = {0.f, 0.f, 0.f};
  const int wv = tid >> 6, ln = tid & 63;

  for (int iter = 0; iter < 100; iter++) {
    float xl[8];
    #pragma unroll
    for (int e = 0; e < 8; e++) xl[e] = fmaf(0.5f, lam[e], X[e].x);

    float sf[3], sp[3];
    #pragma unroll
    for (int k = 0; k < 3; k++) {
      sf[k] = 0.f; sp[k] = 0.f;
      #pragma unroll
      for (int c = 0; c < 4; c++) {
        float2 numl = make_float2(xl[c]     - S[c].x   + U[k][c].x,
                                  X[c].y    - S[c].y   + U[k][c].y);
        float2 numh = make_float2(xl[c+4]   - S[c+4].x + U[k][c+4].x,
                                  X[c+4].y  - S[c+4].y + U[k][c+4].y);
        float dl = fl[c] - om[k], dh = fh[c] - om[k];
        float rl = __builtin_amdgcn_rcpf(fmaf(4000.0f*dl, dl, 1.0f));
        float rh = __builtin_amdgcn_rcpf(fmaf(4000.0f*dh, dh, 1.0f));
        float2 Vl = make_float2(numl.x*rl, numl.y*rl);
        float2 Vh = make_float2(numh.x*rh, numh.y*rh);
        float2 Ul, Uh;
        if (tid == 0 && c == 0) {           // self-paired bins 0 and 1024
          Ul = make_float2(Vl.x, 0.f);
          Uh = make_float2(Vh.x, 0.f);
        } else {                            // Herm: U_l = 0.5*(V_l + conj(V_h))
          Ul = make_float2(0.5f*(Vl.x + Vh.x), 0.5f*(Vl.y - Vh.y));
          Uh = make_float2(Ul.x, -Ul.y);
        }
        S[c].x   += Ul.x - U[k][c].x;   S[c].y   += Ul.y - U[k][c].y;
        S[c+4].x += Uh.x - U[k][c+4].x; S[c+4].y += Uh.y - U[k][c+4].y;
        U[k][c] = Ul; U[k][c+4] = Uh;
        float pw = Uh.x*Uh.x + Uh.y*Uh.y;   // pos-mask: only f>=0 (hi slots)
        sf[k] = fmaf(fh[c], pw, sf[k]);
        sp[k] += pw;
      }
    }

    // stage S into LDS for the lam FFT (barrier shared with the reduction)
    #pragma unroll
    for (int e = 0; e < 8; e++) sbufB[PD(idxs[e])] = S[e];

    // wave-level reduction of the 6 omega scalars
    #pragma unroll
    for (int k = 0; k < 3; k++) {
      #pragma unroll
      for (int off = 32; off >= 1; off >>= 1) {
        sf[k] += __shfl_xor(sf[k], off);
        sp[k] += __shfl_xor(sp[k], off);
      }
    }
    if (ln == 0) {
      #pragma unroll
      for (int k = 0; k < 3; k++) { sred[wv*6 + k] = sf[k]; sred[wv*6 + 3 + k] = sp[k]; }
    }
    __syncthreads();   // covers S writes + sred writes (also guards prev-iter z reads)

    #pragma unroll
    for (int k = 0; k < 3; k++) {
      float a = sred[k] + sred[6+k] + sred[12+k] + sred[18+k];
      float p = sred[3+k] + sred[9+k] + sred[15+k] + sred[21+k];
      om[k] = a / (p + 1e-7f);
    }

    // s_time = (-1)^n * (1/L) * g,  via half-size Hermitian transform
    herm_fft_half(sbufA, sbufB, stwd, tid);

    {
      float2 z0 = sbufA[PD(2*tid)];
      float2 z1 = sbufA[PD(2*tid+1)];
      int rh0 = (tid == 0) ? 512 : (1024 - 2*tid);
      float2 h0 = sbufA[PD(rh0)];
      float2 h1 = sbufA[PD(1023 - 2*tid)];
      float2 h2 = sbufA[PD(1022 - 2*tid)];
      float g[8];
      g[0]=z0.x; g[1]=z0.y; g[2]=z1.x; g[3]=z1.y;
      g[4]=h0.x; g[5]=h1.y; g[6]=h1.x; g[7]=h2.y;
      #pragma unroll
      for (int e = 0; e < 8; e++) {
        float sv = g[e] * inv2048;
        if (e & 1) sv = -sv;
        lam[e] = fmaf(0.001f, xv[e] - sv, lam[e]);
      }
    }
    // no trailing barrier: next iter's combined barrier orders z reads vs A writes
  }

  // final: u_k(time) via the same half-size transform
  #pragma unroll
  for (int k = 0; k < 3; k++) {
    #pragma unroll
    for (int e = 0; e < 8; e++) sbufB[PD(idxs[e])] = U[k][e];
    __syncthreads();
    herm_fft_half(sbufA, sbufB, stwd, tid);
    {
      float2 z0 = sbufA[PD(2*tid)];
      float2 z1 = sbufA[PD(2*tid+1)];
      int rh0 = (tid == 0) ? 512 : (1024 - 2*tid);
      float2 h0 = sbufA[PD(rh0)];
      float2 h1 = sbufA[PD(1023 - 2*tid)];
      float2 h2 = sbufA[PD(1022 - 2*tid)];
      float g[8];
      g[0]=z0.x; g[1]=z0.y; g[2]=z1.x; g[3]=z1.y;
      g[4]=h0.x; g[5]=h1.y; g[6]=h1.x; g[7]=h2.y;
      #pragma unroll
      for (int e = 0; e < 8; e++) {
        float uv = g[e] * inv2048;
        if (e & 1) uv = -uv;
        if (TRANSP) uout[(((size_t)k*8 + b)*32 + d)*2048 + idxs[e]] = uv;   // ws: [k][b][d][l]
        else        uout[(size_t)k*BLD + ((size_t)b*2048 + idxs[e])*32 + d] = uv;
      }
    }
    // next k's __syncthreads orders these z reads vs the next U writes to B
  }
  if (tid == 0) {
    omout[(b*3 + 0)*32 + d] = om[0];
    omout[(b*3 + 1)*32 + d] = om[1];
    omout[(b*3 + 2)*32 + d] = om[2];
  }
}

__global__ void vmd_order(const float* __restrict__ omout, int* __restrict__ ord)
{
  __shared__ float m[24];
  int t = threadIdx.x;
  if (t < 24) {
    float s = 0.f;
    for (int dd = 0; dd < 32; dd++) s += omout[t*32 + dd];
    m[t] = s;
  }
  __syncthreads();
  if (t < 8) {
    float v0 = m[t*3], v1 = m[t*3+1], v2 = m[t*3+2];
    int i0 = 0, i1 = 1, i2 = 2;
    if (v1 < v0){ float tv=v0; v0=v1; v1=tv; int ti=i0; i0=i1; i1=ti; }
    if (v2 < v1){ float tv=v1; v1=v2; v2=tv; int ti=i1; i1=i2; i2=ti; }
    if (v1 < v0){ float tv=v0; v0=v1; v1=tv; int ti=i0; i0=i1; i1=ti; }
    ord[t*3] = i0; ord[t*3+1] = i1; ord[t*3+2] = i2;
  }
}

// ws[ord[k]][b][d][l]  ->  out[k][b][l][d]
__global__ __launch_bounds__(256) void vmd_permute(const float* __restrict__ wsu,
                                                   const int* __restrict__ ord,
                                                   float* __restrict__ out)
{
  __shared__ float tile[32][33];
  int bid = blockIdx.x;
  int lt = bid & 63;
  int b = (bid >> 6) & 7;
  int kpos = bid >> 9;
  int ks = ord[b*3 + kpos];
  int tr = threadIdx.x >> 5;
  int tc = threadIdx.x & 31;
  for (int it = 0; it < 4; it++) {
    int dd = tr + it*8;
    tile[dd][tc] = wsu[(((size_t)ks*8 + b)*32 + dd)*2048 + lt*32 + tc];
  }
  __syncthreads();
  for (int it = 0; it < 4; it++) {
    int ll = tr + it*8;
    out[(size_t)kpos*BLD + ((size_t)b*2048 + lt*32 + ll)*32 + tc] = tile[tc][ll];
  }
}

// fallback: in-place k-plane permutation of d_out
__global__ void vmd_inplace(float* __restrict__ out, const int* __restrict__ ord)
{
  int r = blockIdx.x * 256 + threadIdx.x;   // < 524288
  int b = r >> 16;
  int o0 = ord[b*3], o1 = ord[b*3+1], o2 = ord[b*3+2];
  float v0 = out[(size_t)o0*BLD + r];
  float v1 = out[(size_t)o1*BLD + r];
  float v2 = out[(size_t)o2*BLD + r];
  out[r] = v0;
  out[(size_t)BLD + r] = v1;
  out[(size_t)2*BLD + r] = v2;
}

extern "C" void kernel_launch(void* const* d_in, const int* in_sizes, int n_in,
                              void* d_out, int out_size, void* d_ws, size_t ws_size,
                              hipStream_t stream)
{
  const float* x = (const float*)d_in[0];
  float* out = (float*)d_out;
  const size_t NU = (size_t)3 * BLD;
  size_t need = NU*4 + 768*4 + 24*4;
  if (ws_size >= need) {
    float* wsu  = (float*)d_ws;
    float* wsom = wsu + NU;
    int*   wsord = (int*)(wsom + 768);
    vmd_main<true><<<256, 256, 0, stream>>>(x, wsu, wsom);
    vmd_order<<<1, 64, 0, stream>>>(wsom, wsord);
    vmd_permute<<<1536, 256, 0, stream>>>(wsu, wsord, out);
  } else {
    float* wsom = (float*)d_ws;
    int*   wsord = (int*)(wsom + 768);
    vmd_main<false><<<256, 256, 0, stream>>>(x, out, wsom);
    vmd_order<<<1, 64, 0, stream>>>(wsom, wsord);
    vmd_inplace<<<2048, 256, 0, stream>>>(out, wsord);
  }
}